// Round 5
// baseline (341.740 us; speedup 1.0000x reference)
//
#include <hip/hip_runtime.h>

#define D_IN 128
#define D_H 256
#define D_OUT 128
#define N_SETS 8192

typedef short short8 __attribute__((ext_vector_type(8)));
typedef short short4v __attribute__((ext_vector_type(4)));
typedef float floatx4 __attribute__((ext_vector_type(4)));

__device__ inline unsigned short f32_bf16(float f) {
    unsigned int u = __float_as_uint(f);
    u += 0x7FFFu + ((u >> 16) & 1u);   // round-to-nearest-even
    return (unsigned short)(u >> 16);
}

// blocks [0,32): swizzle W1/W2 into bf16 MFMA fragment order.
// frag f -> 64 lanes x 8 bf16, lane l holds M[k = c*32 + (l>>4)*8 + j][n = nt*16 + (l&15)].
// blocks [32,1064): zero out (8192x128) and counts (8192).
__global__ void setup_kernel(const float* __restrict__ W1, const float* __restrict__ W2,
                             unsigned short* __restrict__ W1s, unsigned short* __restrict__ W2s,
                             float4* __restrict__ out4, float4* __restrict__ cnt4) {
    if (blockIdx.x < 32) {
        int t = blockIdx.x * 256 + threadIdx.x;
        int l = t & 63;
        int f = (t >> 6) & 63;
        int q = l >> 4, r = l & 15;
        if (t < 4096) {                      // W1: 16 n-tiles x 4 k-chunks
            int nt = f >> 2, c = f & 3;
            int k0 = c * 32 + q * 8, n = nt * 16 + r;
            unsigned short v[8];
#pragma unroll
            for (int j = 0; j < 8; j++) v[j] = f32_bf16(W1[(k0 + j) * D_H + n]);
#pragma unroll
            for (int j = 0; j < 8; j++) W1s[f * 512 + l * 8 + j] = v[j];
        } else {                             // W2: 8 n-tiles x 8 k-chunks
            int nt = f >> 3, c = f & 7;
            int k0 = c * 32 + q * 8, n = nt * 16 + r;
            unsigned short v[8];
#pragma unroll
            for (int j = 0; j < 8; j++) v[j] = f32_bf16(W2[(k0 + j) * D_OUT + n]);
#pragma unroll
            for (int j = 0; j < 8; j++) W2s[f * 512 + l * 8 + j] = v[j];
        }
    } else {
        int i = (blockIdx.x - 32) * 256 + threadIdx.x;
        float4 z = make_float4(0.f, 0.f, 0.f, 0.f);
        if (i < 262144) out4[i] = z;               // out: 8192*128 floats
        else if (i < 264192) cnt4[i - 262144] = z; // counts: 8192 floats
    }
}

// 512 blocks x 8 tiles of 64 tokens. 4 waves, n-split: wave w owns h1-col
// tiles {4w..4w+3} (layer 1 transposed: A=W1-frag, B=x-frag) and out-col
// tiles {2w,2w+1}. W1 slice persistent in 64 VGPRs; W2 slice hoisted per
// tile (transient 64 VGPRs); x(t+1) prefetched to regs during phase 1.
// LDS: xA [64][136]bf16 | h1A [64][266]bf16, h2 slabs (4x[32][66]f32)
// overlay h1A after B2. 3 barriers/tile.
__global__ __launch_bounds__(256, 2) void ds_main(
    const float* __restrict__ x, const int* __restrict__ seg,
    const unsigned short* __restrict__ W1s, const float* __restrict__ b1,
    const unsigned short* __restrict__ W2s, const float* __restrict__ b2,
    float* __restrict__ out, float* __restrict__ counts)
{
    __shared__ unsigned char smraw[17408 + 34048];
    unsigned short* xA  = (unsigned short*)smraw;             // [64][136] bf16
    unsigned short* h1A = (unsigned short*)(smraw + 17408);   // [64][266] bf16
    float* h2base = (float*)(smraw + 17408);                  // overlay: 4 x [32][66] f32
    __shared__ int sseg[2][64];

    const int tid = threadIdx.x;
    const int wave = tid >> 6, lane = tid & 63;
    const int r = lane & 15, q = lane >> 4;
    const int blockBase = blockIdx.x * 512;
    const int prow = tid >> 2, pp = tid & 3;      // x staging: row, 32-float chunk

    // ---- persistent weights: W1 slice (16 frags = 64 VGPRs) + biases ----
    short8 w1f[4][4];
#pragma unroll
    for (int nti = 0; nti < 4; nti++)
#pragma unroll
        for (int c = 0; c < 4; c++)
            w1f[nti][c] = *(const short8*)(W1s + ((wave * 4 + nti) * 4 + c) * 512 + lane * 8);
    floatx4 b1v[4];
#pragma unroll
    for (int nti = 0; nti < 4; nti++)
        b1v[nti] = *(const floatx4*)(b1 + (wave * 4 + nti) * 16 + q * 4);
    float b2v[2];
#pragma unroll
    for (int n2 = 0; n2 < 2; n2++)
        b2v[n2] = b2[(wave * 2 + n2) * 16 + r];

    // ---- prologue: stage x tile 0 + sseg slot 0 ----
    if (tid < 64) sseg[0][tid] = seg[blockBase + tid];
    {
        const float* xp = x + (size_t)(blockBase + prow) * D_IN + pp * 32;
        unsigned short* dst = xA + prow * 136 + pp * 32;
#pragma unroll
        for (int u = 0; u < 4; u++) {
            float4 v0 = *(const float4*)(xp + u * 8);
            float4 v1 = *(const float4*)(xp + u * 8 + 4);
            short8 w;
            w[0] = (short)f32_bf16(v0.x); w[1] = (short)f32_bf16(v0.y);
            w[2] = (short)f32_bf16(v0.z); w[3] = (short)f32_bf16(v0.w);
            w[4] = (short)f32_bf16(v1.x); w[5] = (short)f32_bf16(v1.y);
            w[6] = (short)f32_bf16(v1.z); w[7] = (short)f32_bf16(v1.w);
            *(short8*)(dst + u * 8) = w;
        }
    }
    __syncthreads();

    for (int t = 0; t < 8; ++t) {
        // ---- prefetch x(t+1) into regs (in flight through phase 1) ----
        float4 pf[8];
        int nseg = 0;
        if (t < 7) {
            const float* xp = x + (size_t)(blockBase + (t + 1) * 64 + prow) * D_IN + pp * 32;
#pragma unroll
            for (int u = 0; u < 4; u++) {
                pf[u * 2]     = *(const float4*)(xp + u * 8);
                pf[u * 2 + 1] = *(const float4*)(xp + u * 8 + 4);
            }
            if (tid < 64) nseg = seg[blockBase + (t + 1) * 64 + tid];
        }

        // ---- x fragments of tile t (B operand of x^T) ----
        short8 xf[4][4];
#pragma unroll
        for (int tt = 0; tt < 4; tt++)
#pragma unroll
            for (int c = 0; c < 4; c++)
                xf[tt][c] = *(const short8*)(xA + (tt * 16 + r) * 136 + c * 32 + q * 8);

        // ---- phase 1 (transposed): D[h1col = nt*16+q*4+i][tok = tt*16+r] ----
#pragma unroll
        for (int nti = 0; nti < 4; nti++) {
            floatx4 acc[4];
#pragma unroll
            for (int tt = 0; tt < 4; tt++) acc[tt] = (floatx4){0.f, 0.f, 0.f, 0.f};
#pragma unroll
            for (int c = 0; c < 4; c++)
#pragma unroll
                for (int tt = 0; tt < 4; tt++)
                    acc[tt] = __builtin_amdgcn_mfma_f32_16x16x32_bf16(w1f[nti][c], xf[tt][c], acc[tt], 0, 0, 0);
            const int nt = wave * 4 + nti;
#pragma unroll
            for (int tt = 0; tt < 4; tt++) {
                short4v pk;
#pragma unroll
                for (int i = 0; i < 4; i++)
                    pk[i] = (short)f32_bf16(fmaxf(acc[tt][i] + b1v[nti][i], 0.f));
                *(short4v*)(h1A + (tt * 16 + r) * 266 + nt * 16 + q * 4) = pk;
            }
        }
        __syncthreads();   // B1: h1 visible; all xf reads of tile t done

        // ---- stage x(t+1) into xA (overwrites tile t; safe post-B1) ----
        if (t < 7) {
            unsigned short* dst = xA + prow * 136 + pp * 32;
#pragma unroll
            for (int u = 0; u < 4; u++) {
                short8 w;
                w[0] = (short)f32_bf16(pf[u * 2].x); w[1] = (short)f32_bf16(pf[u * 2].y);
                w[2] = (short)f32_bf16(pf[u * 2].z); w[3] = (short)f32_bf16(pf[u * 2].w);
                w[4] = (short)f32_bf16(pf[u * 2 + 1].x); w[5] = (short)f32_bf16(pf[u * 2 + 1].y);
                w[6] = (short)f32_bf16(pf[u * 2 + 1].z); w[7] = (short)f32_bf16(pf[u * 2 + 1].w);
                *(short8*)(dst + u * 8) = w;
            }
            if (tid < 64) sseg[(t + 1) & 1][tid] = nseg;
        }

        // ---- phase 2: W2 slice hoisted (L2-hot), then 64 MFMAs ----
        short8 w2f[16];
#pragma unroll
        for (int n2 = 0; n2 < 2; n2++)
#pragma unroll
            for (int kc = 0; kc < 8; kc++)
                w2f[n2 * 8 + kc] = *(const short8*)(W2s + ((wave * 2 + n2) * 8 + kc) * 512 + lane * 8);

        floatx4 acc2[2][4];
#pragma unroll
        for (int n2 = 0; n2 < 2; n2++)
#pragma unroll
            for (int mt = 0; mt < 4; mt++) acc2[n2][mt] = (floatx4){0.f, 0.f, 0.f, 0.f};
#pragma unroll
        for (int kc = 0; kc < 8; kc++) {
            short8 a2[4];
#pragma unroll
            for (int mt = 0; mt < 4; mt++)
                a2[mt] = *(const short8*)(h1A + (mt * 16 + r) * 266 + kc * 32 + q * 8);
#pragma unroll
            for (int n2 = 0; n2 < 2; n2++)
#pragma unroll
                for (int mt = 0; mt < 4; mt++)
                    acc2[n2][mt] = __builtin_amdgcn_mfma_f32_16x16x32_bf16(a2[mt], w2f[n2 * 8 + kc], acc2[n2][mt], 0, 0, 0);
        }
        __syncthreads();   // B2: h1 reads done -> h2 overlay safe; x(t+1) visible

        // ---- epilogue (wave-private slab, DS in-order within wave) ----
        float* myh2 = h2base + wave * (32 * 66);
#pragma unroll
        for (int n2 = 0; n2 < 2; n2++) {
#pragma unroll
            for (int mt = 0; mt < 4; mt++) {
                floatx4 v;
#pragma unroll
                for (int i = 0; i < 4; i++) v[i] = fmaxf(acc2[n2][mt][i] + b2v[n2], 0.f);
                *(floatx4*)(myh2 + (n2 * 16 + r) * 66 + mt * 16 + q * 4) = v;
            }
        }

        const int* ss = sseg[t & 1];
        // counts: run heads (tile-local)
        if (tid < 64) {
            int s = ss[tid];
            if (tid == 0 || ss[tid - 1] != s) {
                int len = 1;
                for (int u = tid + 1; u < 64 && ss[u] == s; ++u) ++len;
                atomicAdd(&counts[s], (float)len);
            }
        }

        // segment sums: lane -> (col = lane&31, half = lane>>5, 32 tokens).
        // Runs touching a half boundary -> atomic; interior runs -> plain store.
        {
            const int c2 = lane & 31, h = lane >> 5;
            const int col = wave * 32 + c2;
            const int t0 = h * 32;
            const int sfirst = ss[t0], slast = ss[t0 + 31];
            const float* hp = myh2 + c2 * 66 + t0;
            int cur = sfirst;
            float sum = 0.f;
#pragma unroll
            for (int g = 0; g < 8; g++) {
                floatx4 v = *(const floatx4*)(hp + g * 4);
#pragma unroll
                for (int e = 0; e < 4; e++) {
                    int s = ss[t0 + g * 4 + e];
                    if (s != cur) {
                        float* dst = &out[(size_t)cur * D_OUT + col];
                        if (cur == sfirst || cur == slast) atomicAdd(dst, sum);
                        else *dst = sum;
                        sum = 0.f; cur = s;
                    }
                    sum += v[e];
                }
            }
            float* dst = &out[(size_t)cur * D_OUT + col];
            if (cur == sfirst || cur == slast) atomicAdd(dst, sum);
            else *dst = sum;
        }
        __syncthreads();   // B3: epilogue h2 reads done before next h1 writes
    }
}

__global__ void div_kernel(float4* __restrict__ out4, const float* __restrict__ counts) {
    int i = blockIdx.x * 256 + threadIdx.x;   // 262144 float4s, 32 per row
    float inv = 1.f / fmaxf(counts[i >> 5], 1.f);
    float4 v = out4[i];
    v.x *= inv; v.y *= inv; v.z *= inv; v.w *= inv;
    out4[i] = v;
}

extern "C" void kernel_launch(void* const* d_in, const int* in_sizes, int n_in,
                              void* d_out, int out_size, void* d_ws, size_t ws_size,
                              hipStream_t stream) {
    const float* x  = (const float*)d_in[0];
    const int* seg  = (const int*)d_in[1];
    const float* W1 = (const float*)d_in[3];
    const float* b1 = (const float*)d_in[4];
    const float* W2 = (const float*)d_in[5];
    const float* b2 = (const float*)d_in[6];
    float* out = (float*)d_out;

    float* counts       = (float*)d_ws;                                   // 32 KB
    unsigned short* W1s = (unsigned short*)((char*)d_ws + 32768);         // 64 KB
    unsigned short* W2s = (unsigned short*)((char*)d_ws + 32768 + 65536); // 64 KB

    hipLaunchKernelGGL(setup_kernel, dim3(1064), dim3(256), 0, stream,
                       W1, W2, W1s, W2s, (float4*)out, (float4*)counts);
    hipLaunchKernelGGL(ds_main, dim3(512), dim3(256), 0, stream,
                       x, seg, W1s, b1, W2s, b2, out, counts);
    hipLaunchKernelGGL(div_kernel, dim3(1024), dim3(256), 0, stream,
                       (float4*)out, counts);
}

// Round 6
// 302.114 us; speedup vs baseline: 1.1312x; 1.1312x over previous
//
#include <hip/hip_runtime.h>

#define D_IN 128
#define D_H 256
#define D_OUT 128
#define N_SETS 8192

typedef short short8 __attribute__((ext_vector_type(8)));
typedef short short4v __attribute__((ext_vector_type(4)));
typedef float floatx4 __attribute__((ext_vector_type(4)));

__device__ inline unsigned short f32_bf16(float f) {
    unsigned int u = __float_as_uint(f);
    u += 0x7FFFu + ((u >> 16) & 1u);   // round-to-nearest-even
    return (unsigned short)(u >> 16);
}

// blocks [0,32): swizzle W1/W2 into bf16 MFMA fragment order.
// frag f -> 64 lanes x 8 bf16, lane l holds M[k = c*32 + (l>>4)*8 + j][n = nt*16 + (l&15)].
// Same bytes serve as B-frag of M and A-frag of M^T (both validated r4/r5).
// blocks [32,1064): zero out (8192x128) and counts (8192).
__global__ void setup_kernel(const float* __restrict__ W1, const float* __restrict__ W2,
                             unsigned short* __restrict__ W1s, unsigned short* __restrict__ W2s,
                             float4* __restrict__ out4, float4* __restrict__ cnt4) {
    if (blockIdx.x < 32) {
        int t = blockIdx.x * 256 + threadIdx.x;
        int l = t & 63;
        int f = (t >> 6) & 63;
        int q = l >> 4, r = l & 15;
        if (t < 4096) {                      // W1: 16 n-tiles x 4 k-chunks
            int nt = f >> 2, c = f & 3;
            int k0 = c * 32 + q * 8, n = nt * 16 + r;
            unsigned short v[8];
#pragma unroll
            for (int j = 0; j < 8; j++) v[j] = f32_bf16(W1[(k0 + j) * D_H + n]);
#pragma unroll
            for (int j = 0; j < 8; j++) W1s[f * 512 + l * 8 + j] = v[j];
        } else {                             // W2: 8 n-tiles x 8 k-chunks
            int nt = f >> 3, c = f & 7;
            int k0 = c * 32 + q * 8, n = nt * 16 + r;
            unsigned short v[8];
#pragma unroll
            for (int j = 0; j < 8; j++) v[j] = f32_bf16(W2[(k0 + j) * D_OUT + n]);
#pragma unroll
            for (int j = 0; j < 8; j++) W2s[f * 512 + l * 8 + j] = v[j];
        }
    } else {
        int i = (blockIdx.x - 32) * 256 + threadIdx.x;
        float4 z = make_float4(0.f, 0.f, 0.f, 0.f);
        if (i < 262144) out4[i] = z;               // out: 8192*128 floats
        else if (i < 264192) cnt4[i - 262144] = z; // counts: 8192 floats
    }
}

// Fully wave-independent: NO __syncthreads anywhere. Wave owns 32 tokens
// (2 m-tiles). Per kc: 8 indep W1-frag + 8 indep W2-frag L2 loads (the 4
// waves of a block fetch the same lines -> L1 reuse). Layer 1 transposed
// (A=W1-frag, B=x-frag; r4-validated) -> b64 slab writes; layer 2 reads
// slab as A-frags (b128), accumulates 8x2 C/D tiles (64 VGPRs). Epilogue
// overlays the slab with h2 [16 col][36] f32, per-lane 8-token run scan,
// fire-and-forget atomics. Wave-private slab: in-order DS pipe = no sync.
__global__ __launch_bounds__(256, 3) void ds_main(
    const float* __restrict__ x, const int* __restrict__ seg,
    const unsigned short* __restrict__ W1s, const float* __restrict__ b1,
    const unsigned short* __restrict__ W2s, const float* __restrict__ b2,
    float* __restrict__ out, float* __restrict__ counts)
{
    __shared__ unsigned short slabs[4][1280];   // per-wave 32x40 bf16 (2560 B); h2 overlay [16][36] f32 (2304 B)
    __shared__ int ssegs[4][32];

    const int tid = threadIdx.x;
    const int wave = tid >> 6, lane = tid & 63;
    const int r = lane & 15, q = lane >> 4;
    const int tok0 = blockIdx.x * 128 + wave * 32;

    unsigned short* slab = slabs[wave];
    int* sseg = ssegs[wave];
    if (lane < 32) sseg[lane] = seg[tok0 + lane];

    // ---- x fragments direct from global (fp32 -> bf16), 2 m-tiles x 4 k-chunks ----
    // Lane (q,r): x[tok0 + mt*16 + r][c*32 + q*8 .. +7]; serves as B-frag of x^T.
    short8 xfb[2][4];
#pragma unroll
    for (int mt = 0; mt < 2; mt++) {
        const float* xp = x + (size_t)(tok0 + mt * 16 + r) * D_IN + q * 8;
#pragma unroll
        for (int c = 0; c < 4; c++) {
            float4 v0 = *(const float4*)(xp + c * 32);
            float4 v1 = *(const float4*)(xp + c * 32 + 4);
            short8 w;
            w[0] = (short)f32_bf16(v0.x); w[1] = (short)f32_bf16(v0.y);
            w[2] = (short)f32_bf16(v0.z); w[3] = (short)f32_bf16(v0.w);
            w[4] = (short)f32_bf16(v1.x); w[5] = (short)f32_bf16(v1.y);
            w[6] = (short)f32_bf16(v1.z); w[7] = (short)f32_bf16(v1.w);
            xfb[mt][c] = w;
        }
    }

    floatx4 acc2[8][2];
#pragma unroll
    for (int i = 0; i < 8; i++) {
        acc2[i][0] = (floatx4){0.f, 0.f, 0.f, 0.f};
        acc2[i][1] = (floatx4){0.f, 0.f, 0.f, 0.f};
    }

    // ---- fused K loop over 8 k-chunks of D_H ----
#pragma unroll
    for (int kc = 0; kc < 8; kc++) {
        // layer 1 (transposed): produce h1 local cols [0,32) = global cols [kc*32, kc*32+32)
#pragma unroll
        for (int t = 0; t < 2; t++) {
            const int nt = kc * 2 + t;
            short8 w1f[4];
#pragma unroll
            for (int c = 0; c < 4; c++)
                w1f[c] = *(const short8*)(W1s + (nt * 4 + c) * 512 + lane * 8);
            floatx4 b1v = *(const floatx4*)(b1 + nt * 16 + q * 4);
            floatx4 acc1[2];
            acc1[0] = (floatx4){0.f, 0.f, 0.f, 0.f};
            acc1[1] = (floatx4){0.f, 0.f, 0.f, 0.f};
#pragma unroll
            for (int c = 0; c < 4; c++) {
                acc1[0] = __builtin_amdgcn_mfma_f32_16x16x32_bf16(w1f[c], xfb[0][c], acc1[0], 0, 0, 0);
                acc1[1] = __builtin_amdgcn_mfma_f32_16x16x32_bf16(w1f[c], xfb[1][c], acc1[1], 0, 0, 0);
            }
            // D[col = nt*16 + q*4+i][tok = mt*16 + r] -> slab[tok][localcol], b64
#pragma unroll
            for (int mt = 0; mt < 2; mt++) {
                short4v pk;
#pragma unroll
                for (int i = 0; i < 4; i++)
                    pk[i] = (short)f32_bf16(fmaxf(acc1[mt][i] + b1v[i], 0.f));
                *(short4v*)(slab + (mt * 16 + r) * 40 + t * 16 + q * 4) = pk;
            }
        }
        // layer 2: A-frags from slab (in-order DS: writes above are visible)
        short8 a2[2];
        a2[0] = *(const short8*)(slab + r * 40 + q * 8);
        a2[1] = *(const short8*)(slab + (16 + r) * 40 + q * 8);
#pragma unroll
        for (int nt2 = 0; nt2 < 8; nt2++) {
            short8 bw = *(const short8*)(W2s + (nt2 * 8 + kc) * 512 + lane * 8);
            acc2[nt2][0] = __builtin_amdgcn_mfma_f32_16x16x32_bf16(a2[0], bw, acc2[nt2][0], 0, 0, 0);
            acc2[nt2][1] = __builtin_amdgcn_mfma_f32_16x16x32_bf16(a2[1], bw, acc2[nt2][1], 0, 0, 0);
        }
    }

    // ---- counts: run heads within this wave's 32 tokens ----
    if (lane < 32) {
        int s = sseg[lane];
        if (lane == 0 || sseg[lane - 1] != s) {
            int len = 1;
            for (int u = lane + 1; u < 32 && sseg[u] == s; ++u) ++len;
            atomicAdd(&counts[s], (float)len);
        }
    }

    // ---- per-lane segment ids for its 8-token quarter (t0 = q*8) ----
    int sid[8];
#pragma unroll
    for (int e = 0; e < 8; e++) sid[e] = sseg[q * 8 + e];

    // ---- epilogue: per nt2, h2 overlay [col r][36] then run-scan + atomics ----
    float* h2 = (float*)slab;
#pragma unroll
    for (int nt2 = 0; nt2 < 8; nt2++) {
        const float bias = b2[nt2 * 16 + r];
#pragma unroll
        for (int mt = 0; mt < 2; mt++) {
            floatx4 v;
#pragma unroll
            for (int i = 0; i < 4; i++) v[i] = fmaxf(acc2[nt2][mt][i] + bias, 0.f);
            *(floatx4*)(h2 + r * 36 + mt * 16 + q * 4) = v;   // [col=r][tok=mt*16+q*4+i]
        }
        // lane (q,r): col = nt2*16 + r, tokens [q*8, q*8+8)
        floatx4 v0 = *(const floatx4*)(h2 + r * 36 + q * 8);
        floatx4 v1 = *(const floatx4*)(h2 + r * 36 + q * 8 + 4);
        const int col = nt2 * 16 + r;
        float sum = v0[0];
#pragma unroll
        for (int e = 1; e < 8; e++) {
            float v = (e < 4) ? v0[e] : v1[e - 4];
            if (sid[e] != sid[e - 1]) {
                atomicAdd(&out[(size_t)sid[e - 1] * D_OUT + col], sum);
                sum = 0.f;
            }
            sum += v;
        }
        atomicAdd(&out[(size_t)sid[7] * D_OUT + col], sum);
    }
}

__global__ void div_kernel(float4* __restrict__ out4, const float* __restrict__ counts) {
    int i = blockIdx.x * 256 + threadIdx.x;   // 262144 float4s, 32 per row
    float inv = 1.f / fmaxf(counts[i >> 5], 1.f);
    float4 v = out4[i];
    v.x *= inv; v.y *= inv; v.z *= inv; v.w *= inv;
    out4[i] = v;
}

extern "C" void kernel_launch(void* const* d_in, const int* in_sizes, int n_in,
                              void* d_out, int out_size, void* d_ws, size_t ws_size,
                              hipStream_t stream) {
    const float* x  = (const float*)d_in[0];
    const int* seg  = (const int*)d_in[1];
    const float* W1 = (const float*)d_in[3];
    const float* b1 = (const float*)d_in[4];
    const float* W2 = (const float*)d_in[5];
    const float* b2 = (const float*)d_in[6];
    float* out = (float*)d_out;

    float* counts       = (float*)d_ws;                                   // 32 KB
    unsigned short* W1s = (unsigned short*)((char*)d_ws + 32768);         // 64 KB
    unsigned short* W2s = (unsigned short*)((char*)d_ws + 32768 + 65536); // 64 KB

    hipLaunchKernelGGL(setup_kernel, dim3(1064), dim3(256), 0, stream,
                       W1, W2, W1s, W2s, (float4*)out, (float4*)counts);
    hipLaunchKernelGGL(ds_main, dim3(2048), dim3(256), 0, stream,
                       x, seg, W1s, b1, W2s, b2, out, counts);
    hipLaunchKernelGGL(div_kernel, dim3(1024), dim3(256), 0, stream,
                       (float4*)out, counts);
}